// Round 4
// baseline (156.034 us; speedup 1.0000x reference)
//
#include <hip/hip_runtime.h>
#include <hip/hip_bf16.h>
#include <stdint.h>

typedef __bf16 bf16x8 __attribute__((ext_vector_type(8)));
typedef float  f32x4  __attribute__((ext_vector_type(4)));

#define D_MODEL 512
#define N_HEAD  8
#define HD      64
#define L_      1024
#define SCALE   0.125f
#define EXP_NEG8 3.35462628e-4f   // exp(-8), the masked-score probability exp(1e-9 - 8)

__device__ __forceinline__ unsigned short f2bf(float f) {
  unsigned int u = __builtin_bit_cast(unsigned int, f);
  u += 0x7FFFu + ((u >> 16) & 1u);
  return (unsigned short)(u >> 16);
}
__device__ __forceinline__ float bf2f(unsigned short h) {
  unsigned int u = ((unsigned int)h) << 16;
  return __builtin_bit_cast(float, u);
}

__device__ __forceinline__ void gld_lds16(const void* g, void* l) {
  __builtin_amdgcn_global_load_lds(
      (const __attribute__((address_space(1))) void*)g,
      (__attribute__((address_space(3))) void*)l, 16, 0, 0);
}

// ---------------- x (f32) -> bf16 ----------------
__global__ __launch_bounds__(256) void k_cvt_x(const float* __restrict__ x,
                                               unsigned short* __restrict__ xbf) {
  int t = blockIdx.x * 256 + threadIdx.x;
  const float4* p = reinterpret_cast<const float4*>(x) + (size_t)t * 2;
  float4 a = p[0], b = p[1];
  ushort4 o0 = { f2bf(a.x), f2bf(a.y), f2bf(a.z), f2bf(a.w) };
  ushort4 o1 = { f2bf(b.x), f2bf(b.y), f2bf(b.z), f2bf(b.w) };
  ushort4* q = reinterpret_cast<ushort4*>(xbf) + (size_t)t * 2;
  q[0] = o0; q[1] = o1;
}

// ---------------- W_qkv [512,1536] f32 -> Wt [1536,512] bf16 ----------------
__global__ __launch_bounds__(256) void k_cvt_wt(const float* __restrict__ W,
                                                unsigned short* __restrict__ Wt) {
  __shared__ float tile[32][33];
  int kb = blockIdx.x;
  int nb = blockIdx.y;
  int t = threadIdx.x;
  int r = t >> 3, c4 = (t & 7) * 4;
  float4 v = *reinterpret_cast<const float4*>(W + (size_t)(kb * 32 + r) * 1536 + nb * 32 + c4);
  tile[r][c4 + 0] = v.x; tile[r][c4 + 1] = v.y; tile[r][c4 + 2] = v.z; tile[r][c4 + 3] = v.w;
  __syncthreads();
  int a = t >> 3, b4 = (t & 7) * 4;
  ushort4 o = { f2bf(tile[b4 + 0][a]), f2bf(tile[b4 + 1][a]),
                f2bf(tile[b4 + 2][a]), f2bf(tile[b4 + 3][a]) };
  *reinterpret_cast<ushort4*>(Wt + (size_t)(nb * 32 + a) * 512 + kb * 32 + b4) = o;
}

// ---------------- QKV = Xbf @ Wt^T -> [8192, 1536] bf16 (LDS-staged, XCD-swizzled) ----------------
__global__ __launch_bounds__(256, 3) void k_gemm_qkv(const unsigned short* __restrict__ Xbf,
                                                     const unsigned short* __restrict__ Wt,
                                                     unsigned short* __restrict__ QKV) {
  __shared__ unsigned short As[2][128][32];
  __shared__ unsigned short Bs[2][128][32];
  // XCD-aware remap: 768 blocks, each XCD gets a contiguous 1024-row m-panel (all 12 n-blocks)
  int lin = blockIdx.y * 64 + blockIdx.x;
  int xcd = lin & 7, idx = lin >> 3;          // idx 0..95
  int bx = xcd * 8 + idx / 12;
  int by = idx % 12;
  int m0 = bx * 128;
  int n0 = by * 128;
  int w = threadIdx.x >> 6, lane = threadIdx.x & 63;
  int lr = lane & 15, g = lane >> 4;
  int wm = (w >> 1) * 64, wn = (w & 1) * 64;
  int srow = lane >> 2, schk = (lane & 3) * 8;

  auto stage = [&](int buf, int k0) {
#pragma unroll
    for (int j = 0; j < 2; ++j) {
      int row = w * 32 + j * 16 + srow;
      gld_lds16(Xbf + (size_t)(m0 + row) * 512 + k0 + schk, &As[buf][w * 32 + j * 16][0]);
      gld_lds16(Wt  + (size_t)(n0 + row) * 512 + k0 + schk, &Bs[buf][w * 32 + j * 16][0]);
    }
  };

  f32x4 acc[4][4];
  for (int i = 0; i < 4; ++i) for (int j = 0; j < 4; ++j) acc[i][j] = (f32x4){0.f, 0.f, 0.f, 0.f};

  stage(0, 0);
  __syncthreads();

  for (int it = 0; it < 16; ++it) {
    int cur = it & 1;
    if (it < 15) stage(cur ^ 1, (it + 1) * 32);
    bf16x8 a[4], b[4];
#pragma unroll
    for (int mt = 0; mt < 4; ++mt)
      a[mt] = __builtin_bit_cast(bf16x8, *reinterpret_cast<const uint4*>(&As[cur][wm + mt * 16 + lr][g * 8]));
#pragma unroll
    for (int nt = 0; nt < 4; ++nt)
      b[nt] = __builtin_bit_cast(bf16x8, *reinterpret_cast<const uint4*>(&Bs[cur][wn + nt * 16 + lr][g * 8]));
#pragma unroll
    for (int mt = 0; mt < 4; ++mt)
#pragma unroll
      for (int nt = 0; nt < 4; ++nt)
        acc[mt][nt] = __builtin_amdgcn_mfma_f32_16x16x32_bf16(a[mt], b[nt], acc[mt][nt], 0, 0, 0);
    __syncthreads();
  }

#pragma unroll
  for (int mt = 0; mt < 4; ++mt)
#pragma unroll
    for (int nt = 0; nt < 4; ++nt)
#pragma unroll
      for (int r = 0; r < 4; ++r) {
        int m = m0 + wm + mt * 16 + g * 4 + r;
        int n = n0 + wn + nt * 16 + lr;
        QKV[(size_t)m * 1536 + n] = f2bf(acc[mt][nt][r]);
      }
}

// ---------------- Vt[b,h,d,l] <- QKV v-columns ----------------
__global__ __launch_bounds__(256) void k_vtrans(const unsigned short* __restrict__ QKV,
                                                unsigned short* __restrict__ Vt) {
  __shared__ unsigned short tile[64][72];
  int bh = blockIdx.x;
  int lt = blockIdx.y;
  int b = bh >> 3, h = bh & 7;
  int t = threadIdx.x;
  int i = t >> 2, d0 = (t & 3) * 16;
  const uint4* src = reinterpret_cast<const uint4*>(
      QKV + (size_t)(b * L_ + lt * 64 + i) * 1536 + 2 * D_MODEL + h * HD + d0);
  uint4 v0 = src[0], v1 = src[1];
  *reinterpret_cast<uint4*>(&tile[i][d0])     = v0;
  *reinterpret_cast<uint4*>(&tile[i][d0 + 8]) = v1;
  __syncthreads();
  int dd = t >> 2, c0 = (t & 3) * 16;
  unsigned short o[16];
  for (int j = 0; j < 16; ++j) o[j] = tile[c0 + j][dd];
  uint4* dst = reinterpret_cast<uint4*>(Vt + (size_t)(bh * HD + dd) * L_ + lt * 64 + c0);
  dst[0] = *reinterpret_cast<const uint4*>(&o[0]);
  dst[1] = *reinterpret_cast<const uint4*>(&o[8]);
}

// ---------------- sin/cos tables: SCF[l][d] f32, SBF bf16 ----------------
__global__ __launch_bounds__(256) void k_stab(float* __restrict__ SCF,
                                              unsigned short* __restrict__ SBF) {
  int tid = blockIdx.x * 256 + threadIdx.x;
  int l = tid >> 6, d = tid & 63;
  const float kInv = -9.210340371976184f / 31.0f;  // -ln(10000)/31
  float f = expf((float)(d & 31) * kInv);
  float ang = (float)l * f;
  float v = (d < 32) ? sinf(ang) : cosf(ang);
  SCF[tid] = v;
  SBF[tid] = f2bf(v);
}

// ---------------- Aq[bh][l][64] = rot(w_kr @ (q + rwb), pos=l) ----------------
__global__ __launch_bounds__(256) void k_aq(const unsigned short* __restrict__ QKV,
                                            const float* __restrict__ wkr,
                                            const float* __restrict__ rwb,
                                            const float* __restrict__ SCF,
                                            unsigned short* __restrict__ Aq) {
  __shared__ float wkrS[64][65];
  __shared__ float qS[64][65];
  __shared__ float zS[64][65];
  int blk = blockIdx.x;
  int bh = blk >> 4, lt = blk & 15;
  int b = bh >> 3, h = bh & 7;
  int t = threadIdx.x;
  for (int idx = t; idx < 4096; idx += 256) wkrS[idx >> 6][idx & 63] = wkr[idx];
  {
    int r = t >> 2, c0 = (t & 3) * 16;
    const unsigned short* qp = QKV + (size_t)(b * L_ + lt * 64 + r) * 1536 + h * HD;
    for (int jj = 0; jj < 16; ++jj) qS[r][c0 + jj] = bf2f(qp[c0 + jj]) + rwb[h * HD + c0 + jj];
  }
  __syncthreads();
  {
    int r = t >> 2, e0 = (t & 3) * 16;
    float acc[16];
    for (int ii = 0; ii < 16; ++ii) acc[ii] = 0.f;
    for (int d = 0; d < 64; ++d) {
      float qv = qS[r][d];
      for (int ii = 0; ii < 16; ++ii) acc[ii] += wkrS[e0 + ii][d] * qv;
    }
    for (int ii = 0; ii < 16; ++ii) zS[r][e0 + ii] = acc[ii];
  }
  __syncthreads();
  {
    int r = t >> 2, d0 = (t & 3) * 16;
    int pos = lt * 64 + r;
    const float* sc = SCF + (size_t)pos * 64;
    unsigned short* ap = Aq + ((size_t)bh * L_ + lt * 64 + r) * 64;
    for (int jj = 0; jj < 16; ++jj) {
      int d = d0 + jj;
      float a;
      if (d < 32) a = zS[r][d] * sc[d + 32] + zS[r][d + 32] * sc[d];
      else        a = zS[r][d] * sc[d]      - zS[r][d - 32] * sc[d - 32];
      ap[d] = f2bf(a);
    }
  }
}

// ---------------- fused relative attention: QBLK=64, swapped QK^T, 4 blocks/CU ----------------
__global__ __launch_bounds__(256, 4) void k_attn(const unsigned short* __restrict__ QKV,
                                                 const unsigned short* __restrict__ Vt,
                                                 const unsigned short* __restrict__ Sbf,
                                                 const unsigned short* __restrict__ Aq,
                                                 const int* __restrict__ mask,
                                                 const float* __restrict__ rrb,
                                                 float* __restrict__ out) {
  __shared__ unsigned short KtS[2][64][64];   // 16 KB, source-swizzled K tiles
  __shared__ unsigned short VtS[2][64][64];   // 16 KB, source-swizzled V^T tiles
  __shared__ unsigned short pS[4][16][64];    // 8 KB, per-wave P buffer, XOR-swizzled

  // XCD-aware remap: 1024 blocks; XCD x gets logical blocks [x*128, (x+1)*128) = 8 bh-groups
  int n_ = blockIdx.x;
  int l = (n_ & 7) * 128 + (n_ >> 3);
  int bh = l >> 4, qt = l & 15;
  int b = bh >> 3, h = bh & 7;
  int w = threadIdx.x >> 6, lane = threadIdx.x & 63;
  int lr = lane & 15, g = lane >> 4;
  int qw0 = qt * 64 + w * 16;
  int rsub = lane >> 3;
  int csub = (lane & 7) ^ rsub;
  int swz = lr & 7;

  // q fragments (lane lr holds q-row qw0+lr), scale 0.125 folded in (exact in bf16)
  bf16x8 qrr[2], qa[2];
  {
    const unsigned short* qrow = QKV + (size_t)(b * L_ + qw0 + lr) * 1536 + h * HD;
    const unsigned short* arow = Aq + ((size_t)bh * L_ + qw0 + lr) * HD;
#pragma unroll
    for (int ks = 0; ks < 2; ++ks) {
      uint4 raw  = *reinterpret_cast<const uint4*>(qrow + ks * 32 + g * 8);
      uint4 araw = *reinterpret_cast<const uint4*>(arow + ks * 32 + g * 8);
      unsigned short* rb = reinterpret_cast<unsigned short*>(&raw);
      unsigned short* ab = reinterpret_cast<unsigned short*>(&araw);
      unsigned short arr[8], aarr[8];
      for (int j = 0; j < 8; ++j) {
        int d = ks * 32 + g * 8 + j;
        arr[j]  = f2bf((bf2f(rb[j]) + rrb[h * HD + d]) * SCALE);
        aarr[j] = f2bf(bf2f(ab[j]) * SCALE);
      }
      qrr[ks] = __builtin_bit_cast(bf16x8, *reinterpret_cast<uint4*>(arr));
      qa[ks]  = __builtin_bit_cast(bf16x8, *reinterpret_cast<uint4*>(aarr));
    }
  }

  auto stage = [&](int nb, int k0n) {
#pragma unroll
    for (int j = 0; j < 2; ++j) {
      int row = w * 16 + j * 8;
      const unsigned short* gK = QKV + (size_t)(b * L_ + k0n + row + rsub) * 1536 +
                                 D_MODEL + h * HD + csub * 8;
      gld_lds16(gK, &KtS[nb][row][0]);
      const unsigned short* gV = Vt + (size_t)(bh * HD + row + rsub) * L_ + k0n + csub * 8;
      gld_lds16(gV, &VtS[nb][row][0]);
    }
  };

  stage(0, 0);

  float lsum = 0.f;                 // per-lane partial denominator for q = qw0 + lr
  f32x4 accO[4];
#pragma unroll
  for (int nt = 0; nt < 4; ++nt) accO[nt] = (f32x4){0.f, 0.f, 0.f, 0.f};

  char* psw = (char*)&pS[w][0][0];
  __syncthreads();

  for (int it = 0; it < 16; ++it) {
    int k0 = it << 6;
    int cur = it & 1;
    if (it < 15) stage(cur ^ 1, k0 + 64);

    // s-table fragments (L2-hot, shared by all blocks) — issued early to hide latency
    bf16x8 sf[4][2];
#pragma unroll
    for (int t4 = 0; t4 < 4; ++t4)
#pragma unroll
      for (int ks = 0; ks < 2; ++ks)
        sf[t4][ks] = __builtin_bit_cast(bf16x8, *reinterpret_cast<const uint4*>(
            Sbf + (size_t)(k0 + t4 * 16 + lr) * HD + ks * 32 + g * 8));
    int4 mk[4];
#pragma unroll
    for (int t4 = 0; t4 < 4; ++t4)
      mk[t4] = *reinterpret_cast<const int4*>(mask + b * L_ + k0 + t4 * 16 + g * 4);

    // swapped scores: C[k][q] — lane holds q = lr, k = t4*16 + g*4 + r
    f32x4 ac[4];
#pragma unroll
    for (int t4 = 0; t4 < 4; ++t4) ac[t4] = (f32x4){0.f, 0.f, 0.f, 0.f};
#pragma unroll
    for (int t4 = 0; t4 < 4; ++t4)
#pragma unroll
      for (int ks = 0; ks < 2; ++ks) {
        const unsigned short* kp = &KtS[cur][t4 * 16 + lr][((((ks << 2) | g) ^ swz) << 3)];
        bf16x8 kfr = __builtin_bit_cast(bf16x8, *reinterpret_cast<const uint4*>(kp));
        ac[t4] = __builtin_amdgcn_mfma_f32_16x16x32_bf16(kfr, qrr[ks], ac[t4], 0, 0, 0);
      }
#pragma unroll
    for (int t4 = 0; t4 < 4; ++t4)
#pragma unroll
      for (int ks = 0; ks < 2; ++ks)
        ac[t4] = __builtin_amdgcn_mfma_f32_16x16x32_bf16(sf[t4][ks], qa[ks], ac[t4], 0, 0, 0);

    // softmax (constant max 8) + pack 4 contiguous-k bf16 + one b64 write per t4
#pragma unroll
    for (int t4 = 0; t4 < 4; ++t4) {
      float p0 = mk[t4].x ? __expf(ac[t4][0] - 8.f) : EXP_NEG8;
      float p1 = mk[t4].y ? __expf(ac[t4][1] - 8.f) : EXP_NEG8;
      float p2 = mk[t4].z ? __expf(ac[t4][2] - 8.f) : EXP_NEG8;
      float p3 = mk[t4].w ? __expf(ac[t4][3] - 8.f) : EXP_NEG8;
      lsum += (p0 + p1) + (p2 + p3);
      unsigned int lo, hi;
      asm("v_cvt_pk_bf16_f32 %0, %1, %2" : "=v"(lo) : "v"(p0), "v"(p1));
      asm("v_cvt_pk_bf16_f32 %0, %1, %2" : "=v"(hi) : "v"(p2), "v"(p3));
      uint2 pk; pk.x = lo; pk.y = hi;
      *reinterpret_cast<uint2*>(psw + (lr * 128 + (((t4 << 5) | (g << 3)) ^ (swz << 4)))) = pk;
    }

    // P fragments (A-operand: row q=lr, k contiguous) + PV
    bf16x8 pa[2];
#pragma unroll
    for (int ks = 0; ks < 2; ++ks)
      pa[ks] = __builtin_bit_cast(bf16x8, *reinterpret_cast<const uint4*>(
          psw + (lr * 128 + (((ks << 6) | (g << 4)) ^ (swz << 4)))));
#pragma unroll
    for (int nt = 0; nt < 4; ++nt)
#pragma unroll
      for (int ks = 0; ks < 2; ++ks) {
        const unsigned short* vp = &VtS[cur][nt * 16 + lr][((((ks << 2) | g) ^ swz) << 3)];
        bf16x8 vfr = __builtin_bit_cast(bf16x8, *reinterpret_cast<const uint4*>(vp));
        accO[nt] = __builtin_amdgcn_mfma_f32_16x16x32_bf16(pa[ks], vfr, accO[nt], 0, 0, 0);
      }
    __syncthreads();
  }

  // denominator: combine the 4 g-group partials for each q=lr, then redistribute to C layout
  lsum += __shfl_xor(lsum, 16);
  lsum += __shfl_xor(lsum, 32);
  float dsum[4];
#pragma unroll
  for (int r = 0; r < 4; ++r) dsum[r] = __shfl(lsum, g * 4 + r);

#pragma unroll
  for (int nt = 0; nt < 4; ++nt)
#pragma unroll
    for (int r = 0; r < 4; ++r) {
      int q = qw0 + g * 4 + r;
      out[(size_t)(b * L_ + q) * D_MODEL + h * HD + nt * 16 + lr] = accO[nt][r] / dsum[r];
    }
}

extern "C" void kernel_launch(void* const* d_in, const int* in_sizes, int n_in,
                              void* d_out, int out_size, void* d_ws, size_t ws_size,
                              hipStream_t stream) {
  const float* x    = (const float*)d_in[0];
  const int*   mask = (const int*)d_in[1];
  const float* Wqkv = (const float*)d_in[2];
  const float* rrb  = (const float*)d_in[3];
  const float* rwb  = (const float*)d_in[4];
  const float* wkr  = (const float*)d_in[5];
  float* out = (float*)d_out;

  char* ws = (char*)d_ws;
  size_t off = 0;
  unsigned short* XBF = (unsigned short*)(ws + off); off += (size_t)8192 * 512 * 2;
  unsigned short* WT  = (unsigned short*)(ws + off); off += (size_t)1536 * 512 * 2;
  unsigned short* QKV = (unsigned short*)(ws + off); off += (size_t)8192 * 1536 * 2;
  unsigned short* VT  = (unsigned short*)(ws + off); off += (size_t)64 * 64 * 1024 * 2;
  float*          SCF = (float*)(ws + off);          off += (size_t)1024 * 64 * 4;
  unsigned short* SBF = (unsigned short*)(ws + off); off += (size_t)1024 * 64 * 2;
  unsigned short* AQ  = XBF;  // XBF dead after k_gemm_qkv

  hipLaunchKernelGGL(k_cvt_x,    dim3(2048),   dim3(256), 0, stream, x, XBF);
  hipLaunchKernelGGL(k_cvt_wt,   dim3(16, 48), dim3(256), 0, stream, Wqkv, WT);
  hipLaunchKernelGGL(k_stab,     dim3(256),    dim3(256), 0, stream, SCF, SBF);
  hipLaunchKernelGGL(k_gemm_qkv, dim3(64, 12), dim3(256), 0, stream, XBF, WT, QKV);
  hipLaunchKernelGGL(k_vtrans,   dim3(64, 16), dim3(256), 0, stream, QKV, VT);
  hipLaunchKernelGGL(k_aq,       dim3(1024),   dim3(256), 0, stream, QKV, wkr, rwb, SCF, AQ);
  hipLaunchKernelGGL(k_attn,     dim3(1024),   dim3(256), 0, stream, QKV, VT, SBF, AQ, mask, rrb, out);
}

// Round 5
// 113.761 us; speedup vs baseline: 1.3716x; 1.3716x over previous
//
#include <hip/hip_runtime.h>
#include <hip/hip_bf16.h>
#include <stdint.h>

typedef __bf16 bf16x8 __attribute__((ext_vector_type(8)));
typedef float  f32x4  __attribute__((ext_vector_type(4)));

#define D_MODEL 512
#define N_HEAD  8
#define HD      64
#define L_      1024
#define SCALE   0.125f
#define EXP_NEG8 3.35462628e-4f   // exp(1e-9 - 8) ~= exp(-8)
#define L2E     1.44269504f
#define NEG8L2E -11.54156036f     // -8 * log2(e)

__device__ __forceinline__ unsigned short f2bf(float f) {
  unsigned int u = __builtin_bit_cast(unsigned int, f);
  u += 0x7FFFu + ((u >> 16) & 1u);
  return (unsigned short)(u >> 16);
}
__device__ __forceinline__ float bf2f(unsigned short h) {
  unsigned int u = ((unsigned int)h) << 16;
  return __builtin_bit_cast(float, u);
}

__device__ __forceinline__ void gld_lds16(const void* g, void* l) {
  __builtin_amdgcn_global_load_lds(
      (const __attribute__((address_space(1))) void*)g,
      (__attribute__((address_space(3))) void*)l, 16, 0, 0);
}
__device__ __forceinline__ void gld_lds4(const void* g, void* l) {
  __builtin_amdgcn_global_load_lds(
      (const __attribute__((address_space(1))) void*)g,
      (__attribute__((address_space(3))) void*)l, 4, 0, 0);
}

// ---------------- x (f32) -> bf16 ----------------
__global__ __launch_bounds__(256) void k_cvt_x(const float* __restrict__ x,
                                               unsigned short* __restrict__ xbf) {
  int t = blockIdx.x * 256 + threadIdx.x;
  const float4* p = reinterpret_cast<const float4*>(x) + (size_t)t * 2;
  float4 a = p[0], b = p[1];
  ushort4 o0 = { f2bf(a.x), f2bf(a.y), f2bf(a.z), f2bf(a.w) };
  ushort4 o1 = { f2bf(b.x), f2bf(b.y), f2bf(b.z), f2bf(b.w) };
  ushort4* q = reinterpret_cast<ushort4*>(xbf) + (size_t)t * 2;
  q[0] = o0; q[1] = o1;
}

// ---------------- W_qkv [512,1536] f32 -> Wt [1536,512] bf16 ----------------
__global__ __launch_bounds__(256) void k_cvt_wt(const float* __restrict__ W,
                                                unsigned short* __restrict__ Wt) {
  __shared__ float tile[32][33];
  int kb = blockIdx.x;
  int nb = blockIdx.y;
  int t = threadIdx.x;
  int r = t >> 3, c4 = (t & 7) * 4;
  float4 v = *reinterpret_cast<const float4*>(W + (size_t)(kb * 32 + r) * 1536 + nb * 32 + c4);
  tile[r][c4 + 0] = v.x; tile[r][c4 + 1] = v.y; tile[r][c4 + 2] = v.z; tile[r][c4 + 3] = v.w;
  __syncthreads();
  int a = t >> 3, b4 = (t & 7) * 4;
  ushort4 o = { f2bf(tile[b4 + 0][a]), f2bf(tile[b4 + 1][a]),
                f2bf(tile[b4 + 2][a]), f2bf(tile[b4 + 3][a]) };
  *reinterpret_cast<ushort4*>(Wt + (size_t)(nb * 32 + a) * 512 + kb * 32 + b4) = o;
}

// ---------------- sin/cos tables: SCF[l][d] f32, SBF bf16 ----------------
__global__ __launch_bounds__(256) void k_stab(float* __restrict__ SCF,
                                              unsigned short* __restrict__ SBF) {
  int tid = blockIdx.x * 256 + threadIdx.x;
  int l = tid >> 6, d = tid & 63;
  const float kInv = -9.210340371976184f / 31.0f;  // -ln(10000)/31
  float f = expf((float)(d & 31) * kInv);
  float ang = (float)l * f;
  float v = (d < 32) ? sinf(ang) : cosf(ang);
  SCF[tid] = v;
  SBF[tid] = f2bf(v);
}

// ---------------- QKV GEMM with fused epilogue ----------------
// q-slot: (q + rrb)*0.125 ; k-slot: plain ; v: written transposed into Vt
__global__ __launch_bounds__(256, 3) void k_gemm_qkv(const unsigned short* __restrict__ Xbf,
                                                     const unsigned short* __restrict__ Wt,
                                                     const float* __restrict__ rrb,
                                                     unsigned short* __restrict__ QKV,
                                                     unsigned short* __restrict__ Vt) {
  __shared__ unsigned short As[2][128][32];
  __shared__ unsigned short Bs[2][128][32];
  int lin = blockIdx.y * 64 + blockIdx.x;
  int xcd = lin & 7, idx = lin >> 3;
  int bx = xcd * 8 + idx / 12;
  int by = idx % 12;
  int m0 = bx * 128;
  int n0 = by * 128;
  int w = threadIdx.x >> 6, lane = threadIdx.x & 63;
  int lr = lane & 15, g = lane >> 4;
  int wm = (w >> 1) * 64, wn = (w & 1) * 64;
  int srow = lane >> 2, schk = (lane & 3) * 8;

  auto stage = [&](int buf, int k0) {
#pragma unroll
    for (int j = 0; j < 2; ++j) {
      int row = w * 32 + j * 16 + srow;
      gld_lds16(Xbf + (size_t)(m0 + row) * 512 + k0 + schk, &As[buf][w * 32 + j * 16][0]);
      gld_lds16(Wt  + (size_t)(n0 + row) * 512 + k0 + schk, &Bs[buf][w * 32 + j * 16][0]);
    }
  };

  f32x4 acc[4][4];
  for (int i = 0; i < 4; ++i) for (int j = 0; j < 4; ++j) acc[i][j] = (f32x4){0.f, 0.f, 0.f, 0.f};

  stage(0, 0);
  __syncthreads();

  for (int it = 0; it < 16; ++it) {
    int cur = it & 1;
    if (it < 15) stage(cur ^ 1, (it + 1) * 32);
    bf16x8 a[4], b[4];
#pragma unroll
    for (int mt = 0; mt < 4; ++mt)
      a[mt] = __builtin_bit_cast(bf16x8, *reinterpret_cast<const uint4*>(&As[cur][wm + mt * 16 + lr][g * 8]));
#pragma unroll
    for (int nt = 0; nt < 4; ++nt)
      b[nt] = __builtin_bit_cast(bf16x8, *reinterpret_cast<const uint4*>(&Bs[cur][wn + nt * 16 + lr][g * 8]));
#pragma unroll
    for (int mt = 0; mt < 4; ++mt)
#pragma unroll
      for (int nt = 0; nt < 4; ++nt)
        acc[mt][nt] = __builtin_amdgcn_mfma_f32_16x16x32_bf16(a[mt], b[nt], acc[mt][nt], 0, 0, 0);
    __syncthreads();
  }

  int region = n0 >> 9;   // 0=q 1=k 2=v
  if (region == 2) {
    // V: write transposed  Vt[(b*8+h)*64+d][l]
#pragma unroll
    for (int mt = 0; mt < 4; ++mt)
#pragma unroll
      for (int nt = 0; nt < 4; ++nt) {
        int m = m0 + wm + mt * 16 + g * 4;          // l0 (4 consecutive)
        int n = n0 + wn + nt * 16 + lr;
        int nv = n - 1024;
        int bb = m >> 10, h = nv >> 6, d = nv & 63;
        ushort4 o = { f2bf(acc[mt][nt][0]), f2bf(acc[mt][nt][1]),
                      f2bf(acc[mt][nt][2]), f2bf(acc[mt][nt][3]) };
        *reinterpret_cast<ushort4*>(Vt + (size_t)((bb * 8 + h) * 64 + d) * 1024 + (m & 1023)) = o;
      }
  } else if (region == 0) {
#pragma unroll
    for (int mt = 0; mt < 4; ++mt)
#pragma unroll
      for (int nt = 0; nt < 4; ++nt) {
        int n = n0 + wn + nt * 16 + lr;
        float bias = rrb[n];
#pragma unroll
        for (int r = 0; r < 4; ++r) {
          int m = m0 + wm + mt * 16 + g * 4 + r;
          QKV[(size_t)m * 1536 + n] = f2bf((acc[mt][nt][r] + bias) * SCALE);
        }
      }
  } else {
#pragma unroll
    for (int mt = 0; mt < 4; ++mt)
#pragma unroll
      for (int nt = 0; nt < 4; ++nt)
#pragma unroll
        for (int r = 0; r < 4; ++r) {
          int m = m0 + wm + mt * 16 + g * 4 + r;
          int n = n0 + wn + nt * 16 + lr;
          QKV[(size_t)m * 1536 + n] = f2bf(acc[mt][nt][r]);
        }
  }
}

// ---------------- Aq[bh][l][64] = rot(w_kr @ (q + rwb), pos=l) * 0.125 ----------------
// q-slot now holds (q+rrb)*0.125 -> recover q+rwb = qs*8 - rrb + rwb
__global__ __launch_bounds__(256) void k_aq(const unsigned short* __restrict__ QKV,
                                            const float* __restrict__ wkr,
                                            const float* __restrict__ rrb,
                                            const float* __restrict__ rwb,
                                            const float* __restrict__ SCF,
                                            unsigned short* __restrict__ Aq) {
  __shared__ float wkrS[64][65];
  __shared__ float qS[64][65];
  __shared__ float zS[64][65];
  int blk = blockIdx.x;
  int bh = blk >> 4, lt = blk & 15;
  int b = bh >> 3, h = bh & 7;
  int t = threadIdx.x;
  for (int idx = t; idx < 4096; idx += 256) wkrS[idx >> 6][idx & 63] = wkr[idx];
  {
    int r = t >> 2, c0 = (t & 3) * 16;
    const unsigned short* qp = QKV + (size_t)(b * L_ + lt * 64 + r) * 1536 + h * HD;
    for (int jj = 0; jj < 16; ++jj) {
      int d = c0 + jj;
      qS[r][d] = bf2f(qp[d]) * 8.f - rrb[h * HD + d] + rwb[h * HD + d];
    }
  }
  __syncthreads();
  {
    int r = t >> 2, e0 = (t & 3) * 16;
    float acc[16];
    for (int ii = 0; ii < 16; ++ii) acc[ii] = 0.f;
    for (int d = 0; d < 64; ++d) {
      float qv = qS[r][d];
      for (int ii = 0; ii < 16; ++ii) acc[ii] += wkrS[e0 + ii][d] * qv;
    }
    for (int ii = 0; ii < 16; ++ii) zS[r][e0 + ii] = acc[ii];
  }
  __syncthreads();
  {
    int r = t >> 2, d0 = (t & 3) * 16;
    int pos = lt * 64 + r;
    const float* sc = SCF + (size_t)pos * 64;
    unsigned short* ap = Aq + ((size_t)bh * L_ + lt * 64 + r) * 64;
    for (int jj = 0; jj < 16; ++jj) {
      int d = d0 + jj;
      float a;
      if (d < 32) a = zS[r][d] * sc[d + 32] + zS[r][d + 32] * sc[d];
      else        a = zS[r][d] * sc[d]      - zS[r][d - 32] * sc[d - 32];
      ap[d] = f2bf(a * SCALE);
    }
  }
}

// ---------------- fused relative attention: QBLK=128, swapped QK^T ----------------
__global__ __launch_bounds__(256, 2) void k_attn(const unsigned short* __restrict__ QKV,
                                                 const unsigned short* __restrict__ Vt,
                                                 const unsigned short* __restrict__ Sbf,
                                                 const unsigned short* __restrict__ Aq,
                                                 const int* __restrict__ mask,
                                                 float* __restrict__ out) {
  __shared__ unsigned short KtS[2][64][64];   // 16 KB
  __shared__ unsigned short VtS[2][64][64];   // 16 KB
  __shared__ unsigned short SbS[2][64][64];   // 16 KB
  __shared__ int MtS[2][64];                  // 0.5 KB
  __shared__ unsigned short pS[4][32][64];    // 16 KB

  // XCD-aware remap: 512 blocks; each XCD gets 8 full bh-groups (8 qt each)
  int n_ = blockIdx.x;
  int l = (n_ & 7) * 64 + (n_ >> 3);
  int bh = l >> 3, qt = l & 7;
  int b = bh >> 3, h = bh & 7;
  int w = threadIdx.x >> 6, lane = threadIdx.x & 63;
  int lr = lane & 15, g = lane >> 4;
  int qw0 = qt * 128 + w * 32;
  int rsub = lane >> 3;
  int csub = (lane & 7) ^ rsub;
  int swz = lr & 7;

  // q fragments: direct loads (pre-scaled, pre-biased at source)
  bf16x8 qrr[2][2], qa[2][2];
#pragma unroll
  for (int mt = 0; mt < 2; ++mt) {
    const unsigned short* qrow = QKV + (size_t)(b * L_ + qw0 + mt * 16 + lr) * 1536 + h * HD;
    const unsigned short* arow = Aq + ((size_t)bh * L_ + qw0 + mt * 16 + lr) * HD;
#pragma unroll
    for (int ks = 0; ks < 2; ++ks) {
      qrr[mt][ks] = __builtin_bit_cast(bf16x8, *reinterpret_cast<const uint4*>(qrow + ks * 32 + g * 8));
      qa[mt][ks]  = __builtin_bit_cast(bf16x8, *reinterpret_cast<const uint4*>(arow + ks * 32 + g * 8));
    }
  }

  auto stage = [&](int nb, int k0n) {
#pragma unroll
    for (int j = 0; j < 2; ++j) {
      int row = w * 16 + j * 8;
      const unsigned short* gK = QKV + (size_t)(b * L_ + k0n + row + rsub) * 1536 +
                                 D_MODEL + h * HD + csub * 8;
      gld_lds16(gK, &KtS[nb][row][0]);
      const unsigned short* gV = Vt + (size_t)(bh * HD + row + rsub) * L_ + k0n + csub * 8;
      gld_lds16(gV, &VtS[nb][row][0]);
      const unsigned short* gS = Sbf + (size_t)(k0n + row + rsub) * HD + csub * 8;
      gld_lds16(gS, &SbS[nb][row][0]);
    }
    if (w == 0) gld_lds4(mask + b * L_ + k0n + lane, &MtS[nb][0]);
  };

  stage(0, 0);

  float lsum[2] = {0.f, 0.f};       // per-lane denominator partial for q = qw0 + mt*16 + lr
  f32x4 accO[2][4];
#pragma unroll
  for (int mt = 0; mt < 2; ++mt)
#pragma unroll
    for (int nt = 0; nt < 4; ++nt) accO[mt][nt] = (f32x4){0.f, 0.f, 0.f, 0.f};

  char* psw = (char*)&pS[w][0][0];
  __syncthreads();

  for (int it = 0; it < 16; ++it) {
    int k0 = it << 6;
    int cur = it & 1;
    if (it < 15) stage(cur ^ 1, k0 + 64);

    // swapped scores: C[k][q] — lane q = lr, k = t4*16 + g*4 + r
    f32x4 ac[2][4];
#pragma unroll
    for (int mt = 0; mt < 2; ++mt)
#pragma unroll
      for (int t4 = 0; t4 < 4; ++t4) ac[mt][t4] = (f32x4){0.f, 0.f, 0.f, 0.f};
#pragma unroll
    for (int t4 = 0; t4 < 4; ++t4) {
#pragma unroll
      for (int ks = 0; ks < 2; ++ks) {
        const unsigned short* kp = &KtS[cur][t4 * 16 + lr][((((ks << 2) | g) ^ swz) << 3)];
        bf16x8 kfr = __builtin_bit_cast(bf16x8, *reinterpret_cast<const uint4*>(kp));
        ac[0][t4] = __builtin_amdgcn_mfma_f32_16x16x32_bf16(kfr, qrr[0][ks], ac[0][t4], 0, 0, 0);
        ac[1][t4] = __builtin_amdgcn_mfma_f32_16x16x32_bf16(kfr, qrr[1][ks], ac[1][t4], 0, 0, 0);
      }
#pragma unroll
      for (int ks = 0; ks < 2; ++ks) {
        const unsigned short* sp = &SbS[cur][t4 * 16 + lr][((((ks << 2) | g) ^ swz) << 3)];
        bf16x8 sfr = __builtin_bit_cast(bf16x8, *reinterpret_cast<const uint4*>(sp));
        ac[0][t4] = __builtin_amdgcn_mfma_f32_16x16x32_bf16(sfr, qa[0][ks], ac[0][t4], 0, 0, 0);
        ac[1][t4] = __builtin_amdgcn_mfma_f32_16x16x32_bf16(sfr, qa[1][ks], ac[1][t4], 0, 0, 0);
      }
    }

    // softmax (constant max): e = exp2(s*log2e - 8*log2e), cndmask to EXP_NEG8
#pragma unroll
    for (int t4 = 0; t4 < 4; ++t4) {
      int4 mk = *reinterpret_cast<const int4*>(&MtS[cur][t4 * 16 + g * 4]);
#pragma unroll
      for (int mt = 0; mt < 2; ++mt) {
        float e0 = __builtin_amdgcn_exp2f(fmaf(ac[mt][t4][0], L2E, NEG8L2E));
        float e1 = __builtin_amdgcn_exp2f(fmaf(ac[mt][t4][1], L2E, NEG8L2E));
        float e2 = __builtin_amdgcn_exp2f(fmaf(ac[mt][t4][2], L2E, NEG8L2E));
        float e3 = __builtin_amdgcn_exp2f(fmaf(ac[mt][t4][3], L2E, NEG8L2E));
        e0 = mk.x ? e0 : EXP_NEG8;
        e1 = mk.y ? e1 : EXP_NEG8;
        e2 = mk.z ? e2 : EXP_NEG8;
        e3 = mk.w ? e3 : EXP_NEG8;
        lsum[mt] += (e0 + e1) + (e2 + e3);
        unsigned int lo, hi;
        asm("v_cvt_pk_bf16_f32 %0, %1, %2" : "=v"(lo) : "v"(e0), "v"(e1));
        asm("v_cvt_pk_bf16_f32 %0, %1, %2" : "=v"(hi) : "v"(e2), "v"(e3));
        uint2 pk; pk.x = lo; pk.y = hi;
        *reinterpret_cast<uint2*>(psw + ((mt * 16 + lr) * 128 +
            (((t4 << 5) | (g << 3)) ^ (swz << 4)))) = pk;
      }
    }

    // P fragments + PV
    bf16x8 pa[2][2];
#pragma unroll
    for (int mt = 0; mt < 2; ++mt)
#pragma unroll
      for (int ks = 0; ks < 2; ++ks)
        pa[mt][ks] = __builtin_bit_cast(bf16x8, *reinterpret_cast<const uint4*>(
            psw + ((mt * 16 + lr) * 128 + (((ks << 6) | (g << 4)) ^ (swz << 4)))));
#pragma unroll
    for (int nt = 0; nt < 4; ++nt)
#pragma unroll
      for (int ks = 0; ks < 2; ++ks) {
        const unsigned short* vp = &VtS[cur][nt * 16 + lr][((((ks << 2) | g) ^ swz) << 3)];
        bf16x8 vfr = __builtin_bit_cast(bf16x8, *reinterpret_cast<const uint4*>(vp));
        accO[0][nt] = __builtin_amdgcn_mfma_f32_16x16x32_bf16(pa[0][ks], vfr, accO[0][nt], 0, 0, 0);
        accO[1][nt] = __builtin_amdgcn_mfma_f32_16x16x32_bf16(pa[1][ks], vfr, accO[1][nt], 0, 0, 0);
      }
    __syncthreads();
  }

  // denominators: combine 4 g-group partials, redistribute to C layout (row q = g*4+r)
#pragma unroll
  for (int mt = 0; mt < 2; ++mt) {
    lsum[mt] += __shfl_xor(lsum[mt], 16);
    lsum[mt] += __shfl_xor(lsum[mt], 32);
  }
  float dsum[2][4];
#pragma unroll
  for (int mt = 0; mt < 2; ++mt)
#pragma unroll
    for (int r = 0; r < 4; ++r) dsum[mt][r] = __shfl(lsum[mt], g * 4 + r);

#pragma unroll
  for (int mt = 0; mt < 2; ++mt)
#pragma unroll
    for (int nt = 0; nt < 4; ++nt)
#pragma unroll
      for (int r = 0; r < 4; ++r) {
        int q = qw0 + mt * 16 + g * 4 + r;
        out[(size_t)(b * L_ + q) * D_MODEL + h * HD + nt * 16 + lr] = accO[mt][nt][r] / dsum[mt][r];
      }
}

extern "C" void kernel_launch(void* const* d_in, const int* in_sizes, int n_in,
                              void* d_out, int out_size, void* d_ws, size_t ws_size,
                              hipStream_t stream) {
  const float* x    = (const float*)d_in[0];
  const int*   mask = (const int*)d_in[1];
  const float* Wqkv = (const float*)d_in[2];
  const float* rrb  = (const float*)d_in[3];
  const float* rwb  = (const float*)d_in[4];
  const float* wkr  = (const float*)d_in[5];
  float* out = (float*)d_out;

  char* ws = (char*)d_ws;
  size_t off = 0;
  unsigned short* XBF = (unsigned short*)(ws + off); off += (size_t)8192 * 512 * 2;
  unsigned short* WT  = (unsigned short*)(ws + off); off += (size_t)1536 * 512 * 2;
  unsigned short* QKV = (unsigned short*)(ws + off); off += (size_t)8192 * 1536 * 2;
  unsigned short* VT  = (unsigned short*)(ws + off); off += (size_t)64 * 64 * 1024 * 2;
  float*          SCF = (float*)(ws + off);          off += (size_t)1024 * 64 * 4;
  unsigned short* SBF = (unsigned short*)(ws + off); off += (size_t)1024 * 64 * 2;
  unsigned short* AQ  = XBF;  // XBF dead after k_gemm_qkv

  hipLaunchKernelGGL(k_cvt_x,    dim3(2048),   dim3(256), 0, stream, x, XBF);
  hipLaunchKernelGGL(k_cvt_wt,   dim3(16, 48), dim3(256), 0, stream, Wqkv, WT);
  hipLaunchKernelGGL(k_stab,     dim3(256),    dim3(256), 0, stream, SCF, SBF);
  hipLaunchKernelGGL(k_gemm_qkv, dim3(64, 12), dim3(256), 0, stream, XBF, WT, rrb, QKV, VT);
  hipLaunchKernelGGL(k_aq,       dim3(1024),   dim3(256), 0, stream, QKV, wkr, rrb, rwb, SCF, AQ);
  hipLaunchKernelGGL(k_attn,     dim3(512),    dim3(256), 0, stream, QKV, VT, SBF, AQ, mask, out);
}

// Round 6
// 92.754 us; speedup vs baseline: 1.6822x; 1.2265x over previous
//
#include <hip/hip_runtime.h>
#include <hip/hip_bf16.h>
#include <stdint.h>

typedef __bf16 bf16x8 __attribute__((ext_vector_type(8)));
typedef float  f32x4  __attribute__((ext_vector_type(4)));

#define D_MODEL 512
#define N_HEAD  8
#define HD      64
#define L_      1024
#define SCALE   0.125f
#define EXP_NEG8 3.35462628e-4f   // exp(1e-9 - 8) ~= exp(-8)
#define L2E     1.44269504f
#define NEG8L2E -11.54156036f     // -8 * log2(e)

__device__ __forceinline__ unsigned short f2bf(float f) {
  unsigned int u = __builtin_bit_cast(unsigned int, f);
  u += 0x7FFFu + ((u >> 16) & 1u);
  return (unsigned short)(u >> 16);
}
__device__ __forceinline__ float bf2f(unsigned short h) {
  unsigned int u = ((unsigned int)h) << 16;
  return __builtin_bit_cast(float, u);
}

__device__ __forceinline__ void gld_lds16(const void* g, void* l) {
  __builtin_amdgcn_global_load_lds(
      (const __attribute__((address_space(1))) void*)g,
      (__attribute__((address_space(3))) void*)l, 16, 0, 0);
}
__device__ __forceinline__ void gld_lds4(const void* g, void* l) {
  __builtin_amdgcn_global_load_lds(
      (const __attribute__((address_space(1))) void*)g,
      (__attribute__((address_space(3))) void*)l, 4, 0, 0);
}

// ---------------- x (f32) -> bf16 ----------------
__global__ __launch_bounds__(256) void k_cvt_x(const float* __restrict__ x,
                                               unsigned short* __restrict__ xbf) {
  int t = blockIdx.x * 256 + threadIdx.x;
  const float4* p = reinterpret_cast<const float4*>(x) + (size_t)t * 2;
  float4 a = p[0], b = p[1];
  ushort4 o0 = { f2bf(a.x), f2bf(a.y), f2bf(a.z), f2bf(a.w) };
  ushort4 o1 = { f2bf(b.x), f2bf(b.y), f2bf(b.z), f2bf(b.w) };
  ushort4* q = reinterpret_cast<ushort4*>(xbf) + (size_t)t * 2;
  q[0] = o0; q[1] = o1;
}

// ---------------- W_qkv [512,1536] f32 -> Wt [1536,512] bf16 ----------------
__global__ __launch_bounds__(256) void k_cvt_wt(const float* __restrict__ W,
                                                unsigned short* __restrict__ Wt) {
  __shared__ float tile[32][33];
  int kb = blockIdx.x;
  int nb = blockIdx.y;
  int t = threadIdx.x;
  int r = t >> 3, c4 = (t & 7) * 4;
  float4 v = *reinterpret_cast<const float4*>(W + (size_t)(kb * 32 + r) * 1536 + nb * 32 + c4);
  tile[r][c4 + 0] = v.x; tile[r][c4 + 1] = v.y; tile[r][c4 + 2] = v.z; tile[r][c4 + 3] = v.w;
  __syncthreads();
  int a = t >> 3, b4 = (t & 7) * 4;
  ushort4 o = { f2bf(tile[b4 + 0][a]), f2bf(tile[b4 + 1][a]),
                f2bf(tile[b4 + 2][a]), f2bf(tile[b4 + 3][a]) };
  *reinterpret_cast<ushort4*>(Wt + (size_t)(nb * 32 + a) * 512 + kb * 32 + b4) = o;
}

// ---------------- sin/cos tables: SCF[l][d] f32, SBF bf16 ----------------
__global__ __launch_bounds__(256) void k_stab(float* __restrict__ SCF,
                                              unsigned short* __restrict__ SBF) {
  int tid = blockIdx.x * 256 + threadIdx.x;
  int l = tid >> 6, d = tid & 63;
  const float kInv = -9.210340371976184f / 31.0f;  // -ln(10000)/31
  float f = expf((float)(d & 31) * kInv);
  float ang = (float)l * f;
  float v = (d < 32) ? sinf(ang) : cosf(ang);
  SCF[tid] = v;
  SBF[tid] = f2bf(v);
}

// ---------------- Wz rows of Wt: Wt[1536+h*64+e][k] = sum_d wkr[e][d]*Wt[h*64+d][k];
//                  CZ[h*64+e] = sum_d wkr[e][d]*rwb[h][d] ----------------
__global__ __launch_bounds__(256) void k_wz(const unsigned short* __restrict__ Wt,
                                            const float* __restrict__ wkr,
                                            const float* __restrict__ rwb,
                                            unsigned short* __restrict__ Wzt,
                                            float* __restrict__ CZ) {
  __shared__ float wkrS[64][64];
  __shared__ float panS[64][36];
  int blk = blockIdx.x;             // 128 = 8 h * 16 kc
  int h = blk >> 4, kc = blk & 15;  // k-chunk of 32
  int t = threadIdx.x;
  for (int i = t; i < 4096; i += 256) wkrS[i >> 6][i & 63] = wkr[i];
  {
    int d = t >> 2, j0 = (t & 3) * 8;
    const unsigned short* src = Wt + (size_t)(h * 64 + d) * 512 + kc * 32 + j0;
    for (int j = 0; j < 8; ++j) panS[d][j0 + j] = bf2f(src[j]);
  }
  __syncthreads();
  int e = t >> 2, j0 = (t & 3) * 8;
  float acc[8];
  for (int j = 0; j < 8; ++j) acc[j] = 0.f;
  for (int d = 0; d < 64; ++d) {
    float wv = wkrS[e][d];
    for (int j = 0; j < 8; ++j) acc[j] += wv * panS[d][j0 + j];
  }
  unsigned short* dst = Wzt + (size_t)(h * 64 + e) * 512 + kc * 32 + j0;
  ushort4 o0 = { f2bf(acc[0]), f2bf(acc[1]), f2bf(acc[2]), f2bf(acc[3]) };
  ushort4 o1 = { f2bf(acc[4]), f2bf(acc[5]), f2bf(acc[6]), f2bf(acc[7]) };
  *reinterpret_cast<ushort4*>(dst) = o0;
  *reinterpret_cast<ushort4*>(dst + 4) = o1;
  if (kc == 0 && t < 64) {
    float c = 0.f;
    for (int d = 0; d < 64; ++d) c += wkrS[t][d] * rwb[h * 64 + d];
    CZ[h * 64 + t] = c;
  }
}

// ---------------- QKVZ GEMM, N=2048, fused epilogues ----------------
// q: (q+rrb)*0.125 -> QKV ; k: plain -> QKV ; v: transposed -> Vt ;
// z: +cz, rotate by pos, *0.125 -> Aq
__global__ __launch_bounds__(256, 3) void k_gemm_qkv(const unsigned short* __restrict__ Xbf,
                                                     const unsigned short* __restrict__ Wt,
                                                     const float* __restrict__ rrb,
                                                     const float* __restrict__ SCF,
                                                     const float* __restrict__ CZ,
                                                     unsigned short* __restrict__ QKV,
                                                     unsigned short* __restrict__ Vt,
                                                     unsigned short* __restrict__ Aq) {
  __shared__ unsigned short As[2][128][32];
  __shared__ unsigned short Bs[2][128][32];
  int lin = blockIdx.y * 64 + blockIdx.x;     // 1024 blocks
  int xcd = lin & 7, idx = lin >> 3;          // idx 0..127
  int bx = xcd * 8 + idx / 16;
  int by = idx % 16;
  int m0 = bx * 128;
  int n0 = by * 128;
  int w = threadIdx.x >> 6, lane = threadIdx.x & 63;
  int lr = lane & 15, g = lane >> 4;
  int wm = (w >> 1) * 64, wn = (w & 1) * 64;
  int srow = lane >> 2, schk = (lane & 3) * 8;

  auto stage = [&](int buf, int k0) {
#pragma unroll
    for (int j = 0; j < 2; ++j) {
      int row = w * 32 + j * 16 + srow;
      gld_lds16(Xbf + (size_t)(m0 + row) * 512 + k0 + schk, &As[buf][w * 32 + j * 16][0]);
      gld_lds16(Wt  + (size_t)(n0 + row) * 512 + k0 + schk, &Bs[buf][w * 32 + j * 16][0]);
    }
  };

  f32x4 acc[4][4];
  for (int i = 0; i < 4; ++i) for (int j = 0; j < 4; ++j) acc[i][j] = (f32x4){0.f, 0.f, 0.f, 0.f};

  stage(0, 0);
  __syncthreads();

  for (int it = 0; it < 16; ++it) {
    int cur = it & 1;
    if (it < 15) stage(cur ^ 1, (it + 1) * 32);
    bf16x8 a[4], b[4];
#pragma unroll
    for (int mt = 0; mt < 4; ++mt)
      a[mt] = __builtin_bit_cast(bf16x8, *reinterpret_cast<const uint4*>(&As[cur][wm + mt * 16 + lr][g * 8]));
#pragma unroll
    for (int nt = 0; nt < 4; ++nt)
      b[nt] = __builtin_bit_cast(bf16x8, *reinterpret_cast<const uint4*>(&Bs[cur][wn + nt * 16 + lr][g * 8]));
#pragma unroll
    for (int mt = 0; mt < 4; ++mt)
#pragma unroll
      for (int nt = 0; nt < 4; ++nt)
        acc[mt][nt] = __builtin_amdgcn_mfma_f32_16x16x32_bf16(a[mt], b[nt], acc[mt][nt], 0, 0, 0);
    __syncthreads();
  }

  int region = n0 >> 9;   // 0=q 1=k 2=v 3=z
  if (region == 3) {
    int nvb = (n0 - 1536) + wn;     // multiple of 64
    int h = nvb >> 6;
    int bb = m0 >> 10;
    float cz0 = CZ[nvb + lr];
    float cz1 = CZ[nvb + 16 + lr];
    float cz2 = CZ[nvb + 32 + lr];
    float cz3 = CZ[nvb + 48 + lr];
#pragma unroll
    for (int mt = 0; mt < 4; ++mt)
#pragma unroll
      for (int r = 0; r < 4; ++r) {
        int m = m0 + wm + mt * 16 + g * 4 + r;
        int lrow = m & 1023;
        const float* sc = SCF + (size_t)lrow * 64;
        float s0 = sc[lr], s1 = sc[16 + lr], c0 = sc[32 + lr], c1 = sc[48 + lr];
        float z0 = acc[mt][0][r] + cz0;
        float z1 = acc[mt][1][r] + cz1;
        float z2 = acc[mt][2][r] + cz2;
        float z3 = acc[mt][3][r] + cz3;
        unsigned short* ap = Aq + ((size_t)(bb * 8 + h) * 1024 + lrow) * 64;
        ap[lr]      = f2bf((z0 * c0 + z2 * s0) * SCALE);
        ap[16 + lr] = f2bf((z1 * c1 + z3 * s1) * SCALE);
        ap[32 + lr] = f2bf((z2 * c0 - z0 * s0) * SCALE);
        ap[48 + lr] = f2bf((z3 * c1 - z1 * s1) * SCALE);
      }
  } else if (region == 2) {
#pragma unroll
    for (int mt = 0; mt < 4; ++mt)
#pragma unroll
      for (int nt = 0; nt < 4; ++nt) {
        int m = m0 + wm + mt * 16 + g * 4;
        int n = n0 + wn + nt * 16 + lr;
        int nv = n - 1024;
        int bb = m >> 10, h = nv >> 6, d = nv & 63;
        ushort4 o = { f2bf(acc[mt][nt][0]), f2bf(acc[mt][nt][1]),
                      f2bf(acc[mt][nt][2]), f2bf(acc[mt][nt][3]) };
        *reinterpret_cast<ushort4*>(Vt + (size_t)((bb * 8 + h) * 64 + d) * 1024 + (m & 1023)) = o;
      }
  } else if (region == 0) {
#pragma unroll
    for (int mt = 0; mt < 4; ++mt)
#pragma unroll
      for (int nt = 0; nt < 4; ++nt) {
        int n = n0 + wn + nt * 16 + lr;
        float bias = rrb[n];
#pragma unroll
        for (int r = 0; r < 4; ++r) {
          int m = m0 + wm + mt * 16 + g * 4 + r;
          QKV[(size_t)m * 1536 + n] = f2bf((acc[mt][nt][r] + bias) * SCALE);
        }
      }
  } else {
#pragma unroll
    for (int mt = 0; mt < 4; ++mt)
#pragma unroll
      for (int nt = 0; nt < 4; ++nt)
#pragma unroll
        for (int r = 0; r < 4; ++r) {
          int m = m0 + wm + mt * 16 + g * 4 + r;
          int n = n0 + wn + nt * 16 + lr;
          QKV[(size_t)m * 1536 + n] = f2bf(acc[mt][nt][r]);
        }
  }
}

// ---------------- fused relative attention: QBLK=128, swapped QK^T, 3 blocks/CU ----------------
__global__ __launch_bounds__(256, 3) void k_attn(const unsigned short* __restrict__ QKV,
                                                 const unsigned short* __restrict__ Vt,
                                                 const unsigned short* __restrict__ Sbf,
                                                 const unsigned short* __restrict__ Aq,
                                                 const int* __restrict__ mask,
                                                 float* __restrict__ out) {
  __shared__ unsigned short KtS[2][64][64];   // 16 KB
  __shared__ unsigned short VtS[2][64][64];   // 16 KB
  __shared__ int MtS[2][64];                  // 0.5 KB
  __shared__ unsigned short pS[4][32][64];    // 16 KB

  // XCD-aware remap: 512 blocks; each XCD gets 8 full bh-groups (8 qt each)
  int n_ = blockIdx.x;
  int l = (n_ & 7) * 64 + (n_ >> 3);
  int bh = l >> 3, qt = l & 7;
  int b = bh >> 3, h = bh & 7;
  int w = threadIdx.x >> 6, lane = threadIdx.x & 63;
  int lr = lane & 15, g = lane >> 4;
  int qw0 = qt * 128 + w * 32;
  int rsub = lane >> 3;
  int csub = (lane & 7) ^ rsub;
  int swz = lr & 7;

  // q fragments: direct loads (pre-scaled, pre-biased, pre-rotated at source)
  bf16x8 qrr[2][2], qa[2][2];
#pragma unroll
  for (int mt = 0; mt < 2; ++mt) {
    const unsigned short* qrow = QKV + (size_t)(b * L_ + qw0 + mt * 16 + lr) * 1536 + h * HD;
    const unsigned short* arow = Aq + ((size_t)bh * L_ + qw0 + mt * 16 + lr) * HD;
#pragma unroll
    for (int ks = 0; ks < 2; ++ks) {
      qrr[mt][ks] = __builtin_bit_cast(bf16x8, *reinterpret_cast<const uint4*>(qrow + ks * 32 + g * 8));
      qa[mt][ks]  = __builtin_bit_cast(bf16x8, *reinterpret_cast<const uint4*>(arow + ks * 32 + g * 8));
    }
  }

  auto stage = [&](int nb, int k0n) {
#pragma unroll
    for (int j = 0; j < 2; ++j) {
      int row = w * 16 + j * 8;
      const unsigned short* gK = QKV + (size_t)(b * L_ + k0n + row + rsub) * 1536 +
                                 D_MODEL + h * HD + csub * 8;
      gld_lds16(gK, &KtS[nb][row][0]);
      const unsigned short* gV = Vt + (size_t)(bh * HD + row + rsub) * L_ + k0n + csub * 8;
      gld_lds16(gV, &VtS[nb][row][0]);
    }
    if (w == 0) gld_lds4(mask + b * L_ + k0n + lane, &MtS[nb][0]);
  };

  stage(0, 0);

  float lsum[2] = {0.f, 0.f};
  f32x4 accO[2][4];
#pragma unroll
  for (int mt = 0; mt < 2; ++mt)
#pragma unroll
    for (int nt = 0; nt < 4; ++nt) accO[mt][nt] = (f32x4){0.f, 0.f, 0.f, 0.f};

  char* psw = (char*)&pS[w][0][0];
  __syncthreads();

  for (int it = 0; it < 16; ++it) {
    int k0 = it << 6;
    int cur = it & 1;
    if (it < 15) stage(cur ^ 1, k0 + 64);

    // s-table fragments direct from L2 (shared across all 512 blocks)
    bf16x8 sf[4][2];
#pragma unroll
    for (int t4 = 0; t4 < 4; ++t4)
#pragma unroll
      for (int ks = 0; ks < 2; ++ks)
        sf[t4][ks] = __builtin_bit_cast(bf16x8, *reinterpret_cast<const uint4*>(
            Sbf + (size_t)(k0 + t4 * 16 + lr) * HD + ks * 32 + g * 8));

    // swapped scores: C[k][q] — lane q = lr, k = t4*16 + g*4 + r
    f32x4 ac[2][4];
#pragma unroll
    for (int mt = 0; mt < 2; ++mt)
#pragma unroll
      for (int t4 = 0; t4 < 4; ++t4) ac[mt][t4] = (f32x4){0.f, 0.f, 0.f, 0.f};
#pragma unroll
    for (int t4 = 0; t4 < 4; ++t4) {
#pragma unroll
      for (int ks = 0; ks < 2; ++ks) {
        const unsigned short* kp = &KtS[cur][t4 * 16 + lr][((((ks << 2) | g) ^ swz) << 3)];
        bf16x8 kfr = __builtin_bit_cast(bf16x8, *reinterpret_cast<const uint4*>(kp));
        ac[0][t4] = __builtin_amdgcn_mfma_f32_16x16x32_bf16(kfr, qrr[0][ks], ac[0][t4], 0, 0, 0);
        ac[1][t4] = __builtin_amdgcn_mfma_f32_16x16x32_bf16(kfr, qrr[1][ks], ac[1][t4], 0, 0, 0);
      }
#pragma unroll
      for (int ks = 0; ks < 2; ++ks) {
        ac[0][t4] = __builtin_amdgcn_mfma_f32_16x16x32_bf16(sf[t4][ks], qa[0][ks], ac[0][t4], 0, 0, 0);
        ac[1][t4] = __builtin_amdgcn_mfma_f32_16x16x32_bf16(sf[t4][ks], qa[1][ks], ac[1][t4], 0, 0, 0);
      }
    }

    // softmax (constant max): e = exp2(s*log2e - 8*log2e)
#pragma unroll
    for (int t4 = 0; t4 < 4; ++t4) {
      int4 mk = *reinterpret_cast<const int4*>(&MtS[cur][t4 * 16 + g * 4]);
#pragma unroll
      for (int mt = 0; mt < 2; ++mt) {
        float e0 = __builtin_amdgcn_exp2f(fmaf(ac[mt][t4][0], L2E, NEG8L2E));
        float e1 = __builtin_amdgcn_exp2f(fmaf(ac[mt][t4][1], L2E, NEG8L2E));
        float e2 = __builtin_amdgcn_exp2f(fmaf(ac[mt][t4][2], L2E, NEG8L2E));
        float e3 = __builtin_amdgcn_exp2f(fmaf(ac[mt][t4][3], L2E, NEG8L2E));
        e0 = mk.x ? e0 : EXP_NEG8;
        e1 = mk.y ? e1 : EXP_NEG8;
        e2 = mk.z ? e2 : EXP_NEG8;
        e3 = mk.w ? e3 : EXP_NEG8;
        lsum[mt] += (e0 + e1) + (e2 + e3);
        unsigned int lo, hi;
        asm("v_cvt_pk_bf16_f32 %0, %1, %2" : "=v"(lo) : "v"(e0), "v"(e1));
        asm("v_cvt_pk_bf16_f32 %0, %1, %2" : "=v"(hi) : "v"(e2), "v"(e3));
        uint2 pk; pk.x = lo; pk.y = hi;
        *reinterpret_cast<uint2*>(psw + ((mt * 16 + lr) * 128 +
            (((t4 << 5) | (g << 3)) ^ (swz << 4)))) = pk;
      }
    }

    // P fragments + PV
    bf16x8 pa[2][2];
#pragma unroll
    for (int mt = 0; mt < 2; ++mt)
#pragma unroll
      for (int ks = 0; ks < 2; ++ks)
        pa[mt][ks] = __builtin_bit_cast(bf16x8, *reinterpret_cast<const uint4*>(
            psw + ((mt * 16 + lr) * 128 + (((ks << 6) | (g << 4)) ^ (swz << 4)))));
#pragma unroll
    for (int nt = 0; nt < 4; ++nt)
#pragma unroll
      for (int ks = 0; ks < 2; ++ks) {
        const unsigned short* vp = &VtS[cur][nt * 16 + lr][((((ks << 2) | g) ^ swz) << 3)];
        bf16x8 vfr = __builtin_bit_cast(bf16x8, *reinterpret_cast<const uint4*>(vp));
        accO[0][nt] = __builtin_amdgcn_mfma_f32_16x16x32_bf16(pa[0][ks], vfr, accO[0][nt], 0, 0, 0);
        accO[1][nt] = __builtin_amdgcn_mfma_f32_16x16x32_bf16(pa[1][ks], vfr, accO[1][nt], 0, 0, 0);
      }
    __syncthreads();
  }

#pragma unroll
  for (int mt = 0; mt < 2; ++mt) {
    lsum[mt] += __shfl_xor(lsum[mt], 16);
    lsum[mt] += __shfl_xor(lsum[mt], 32);
  }
  float dsum[2][4];
#pragma unroll
  for (int mt = 0; mt < 2; ++mt)
#pragma unroll
    for (int r = 0; r < 4; ++r) dsum[mt][r] = __shfl(lsum[mt], g * 4 + r);

#pragma unroll
  for (int mt = 0; mt < 2; ++mt)
#pragma unroll
    for (int nt = 0; nt < 4; ++nt)
#pragma unroll
      for (int r = 0; r < 4; ++r) {
        int q = qw0 + mt * 16 + g * 4 + r;
        out[(size_t)(b * L_ + q) * D_MODEL + h * HD + nt * 16 + lr] = accO[mt][nt][r] / dsum[mt][r];
      }
}

extern "C" void kernel_launch(void* const* d_in, const int* in_sizes, int n_in,
                              void* d_out, int out_size, void* d_ws, size_t ws_size,
                              hipStream_t stream) {
  const float* x    = (const float*)d_in[0];
  const int*   mask = (const int*)d_in[1];
  const float* Wqkv = (const float*)d_in[2];
  const float* rrb  = (const float*)d_in[3];
  const float* rwb  = (const float*)d_in[4];
  const float* wkr  = (const float*)d_in[5];
  float* out = (float*)d_out;

  char* ws = (char*)d_ws;
  size_t off = 0;
  unsigned short* XBF = (unsigned short*)(ws + off); off += (size_t)8192 * 512 * 2;      // 8 MB
  unsigned short* WT  = (unsigned short*)(ws + off); off += (size_t)2048 * 512 * 2;      // 2 MB
  unsigned short* QKV = (unsigned short*)(ws + off); off += (size_t)8192 * 1536 * 2;     // 24 MB
  unsigned short* VT  = (unsigned short*)(ws + off); off += (size_t)64 * 64 * 1024 * 2;  // 8 MB
  unsigned short* AQ  = (unsigned short*)(ws + off); off += (size_t)64 * 1024 * 64 * 2;  // 8 MB
  float*          SCF = (float*)(ws + off);          off += (size_t)1024 * 64 * 4;       // 256 KB
  unsigned short* SBF = (unsigned short*)(ws + off); off += (size_t)1024 * 64 * 2;       // 128 KB
  float*          CZ  = (float*)(ws + off);          off += 512 * 4;

  hipLaunchKernelGGL(k_cvt_x,    dim3(2048),   dim3(256), 0, stream, x, XBF);
  hipLaunchKernelGGL(k_cvt_wt,   dim3(16, 48), dim3(256), 0, stream, Wqkv, WT);
  hipLaunchKernelGGL(k_stab,     dim3(256),    dim3(256), 0, stream, SCF, SBF);
  hipLaunchKernelGGL(k_wz,       dim3(128),    dim3(256), 0, stream, WT, wkr, rwb, WT + (size_t)1536 * 512, CZ);
  hipLaunchKernelGGL(k_gemm_qkv, dim3(64, 16), dim3(256), 0, stream, XBF, WT, rrb, SCF, CZ, QKV, VT, AQ);
  hipLaunchKernelGGL(k_attn,     dim3(512),    dim3(256), 0, stream, QKV, VT, SBF, AQ, mask, out);
}